// Round 1
// 284.684 us; speedup vs baseline: 1.0437x; 1.0437x over previous
//
#include <hip/hip_runtime.h>

// ---------------- problem constants ----------------
#define B_  8
#define C_  32
#define U_  5
#define V_  5
#define H_  64
#define W_  64

// x / out strides (fp32 elements): [B][32][U][V][H][W]
#define SV_ 4096
#define SU_ 20480
#define SC_ 102400
#define SB_ 3276800

// xT (bf16, padded): [row = ((b*25+u*5+v)*64+h)][cq(4)][wslot(66)][c8(8)]
//   wslot = w+1 ; slots 0 and 65 are zeros (SAME padding in w for free)
//   row stride = 4*66*16 = 4224 B ; cq stride = 1056 B ; total 12800*4224 = 54067200 B
// btab (bf16): per frag f (108): [q(4)][oc(8)][c8(8)] = 512 B  -> 55296 B
#define XROW 4224
#define BT_OFF 54067200ull

typedef short bf16x8 __attribute__((ext_vector_type(8)));
typedef float f32x4 __attribute__((ext_vector_type(4)));

__device__ __forceinline__ unsigned short f2bf(float f) {
    unsigned int u = __builtin_bit_cast(unsigned int, f);
    u = (u + 0x7FFFu + ((u >> 16) & 1u)) >> 16;   // RNE
    return (unsigned short)u;
}

__device__ __forceinline__ f32x4 mfma16(bf16x8 a, bf16x8 b, f32x4 c) {
    return __builtin_amdgcn_mfma_f32_16x16x32_bf16(a, b, c, 0, 0, 0);
}

// ---------------- K1: prep = transpose (blocks 0..3199) + weights (3200..3307) ----------------
__global__ __launch_bounds__(256)
void k_prep(const float* __restrict__ x, unsigned short* __restrict__ xT,
            const float* __restrict__ w0, const float* __restrict__ w1,
            const float* __restrict__ w2, const float* __restrict__ w3,
            unsigned short* __restrict__ btab)
{
    if (blockIdx.x >= 3200) {
        // ---- weight -> A-frag table [f][q(4)][oc(8)][c8(8)] bf16 ----
        const int f = blockIdx.x - 3200;   // 0..107
        const int br = f / 27;
        const int tap = f % 27;
        const float* wp = (br == 0) ? w0 : (br == 1) ? w1 : (br == 2) ? w2 : w3;
        const int q  = threadIdx.x >> 6;
        const int oc = (threadIdx.x >> 3) & 7;
        const int j  = threadIdx.x & 7;
        btab[(size_t)f * 256 + q * 64 + oc * 8 + j] =
            f2bf(wp[(size_t)oc * 864 + (q * 8 + j) * 27 + tap]);
        return;
    }

    // ---- x fp32 [B,C,U,V,H,W] -> padded bf16 xT ----
    __shared__ float tl[C_ * 4 * 64];   // [c][h(4)][w(64)] fp32, 32 KB
    const int tid = threadIdx.x;
    int blk = blockIdx.x;
    const int hq = blk & 15; blk >>= 4;
    const int v = blk % 5; blk /= 5;
    const int u = blk % 5;
    const int b = blk / 5;
    const int h0 = hq * 4;

    const float* src = x + (size_t)b * SB_ + (size_t)u * SU_ + (size_t)v * SV_ + h0 * 64;
#pragma unroll
    for (int i = 0; i < 8; ++i) {
        const int e = tid + i * 256;
        const int c = e >> 6;
        const int rem = e & 63;
        const int h = rem >> 4;
        const int w4 = (rem & 15) * 4;
        const float4 val = *(const float4*)(src + (size_t)c * SC_ + h * 64 + w4);
        *(float4*)(tl + c * 256 + h * 64 + w4) = val;
    }
    __syncthreads();

    const int h = tid >> 6;
    const int w = tid & 63;
    unsigned short* dst = xT + (size_t)((b * 25 + u * 5 + v) * 64 + h0 + h) * (XROW / 2);
    const uint4 z = make_uint4(0u, 0u, 0u, 0u);
#pragma unroll
    for (int cq = 0; cq < 4; ++cq) {
        unsigned short s[8];
#pragma unroll
        for (int j = 0; j < 8; ++j)
            s[j] = f2bf(tl[(cq * 8 + j) * 256 + h * 64 + w]);
        uint4 o;
        o.x = (unsigned)s[0] | ((unsigned)s[1] << 16);
        o.y = (unsigned)s[2] | ((unsigned)s[3] << 16);
        o.z = (unsigned)s[4] | ((unsigned)s[5] << 16);
        o.w = (unsigned)s[6] | ((unsigned)s[7] << 16);
        *(uint4*)(dst + cq * 528 + (w + 1) * 8) = o;           // wslot = w+1
        if (w == 0)  *(uint4*)(dst + cq * 528 + 0)       = z;  // wslot 0
        if (w == 63) *(uint4*)(dst + cq * 528 + 65 * 8)  = z;  // wslot 65
    }
}

// ---------------- K2: main MFMA kernel ----------------
// grid 1600 = 8 b * 25 buv * 8 hs ; block 512 thr = 8 waves
// XCD-chunked: 1600 = 8*200 -> XCD (blk&7) owns batch b=(blk&7) entirely;
//   within XCD, hs varies fastest so the (u,v) 9-neighborhood (~2.4MB) stays L2-resident.
// wave: w-tile (wave&3)*16, h-quad rbase=(wave>>2)*4  -> 4 output rows per wave
//   (each ds_read of a weight frag now feeds 4 mfmas instead of 2 -> LDS pipe halved)
// MFMA: A = W[oc16][c32] (oc = lane&7 repl), B = x[c32][w16], D: w = lane&15, oc = q*4+reg
__global__ __launch_bounds__(512, 2)
void k_main(const unsigned short* __restrict__ xT,
            const unsigned short* __restrict__ btabu,
            const float* __restrict__ bb0, const float* __restrict__ aa0,
            const float* __restrict__ bb1, const float* __restrict__ aa1,
            const float* __restrict__ bb2, const float* __restrict__ aa2,
            const float* __restrict__ bb3, const float* __restrict__ aa3,
            float* __restrict__ out)
{
    __shared__ alignas(16) char wlds[55296];

    const int tid = threadIdx.x;
    const int blk = blockIdx.x;
    const int b   = blk & 7;          // == XCD id (round-robin %8 assignment)
    const int i   = blk >> 3;         // 0..199
    const int buv = i >> 3;           // 0..24
    const int hs  = i & 7;
    const int v = buv % 5;
    const int u = buv / 5;
    const int h0 = hs * 8;

    // stage weight table to LDS (one time)
    {
        const uint4* g = (const uint4*)btabu;
        uint4* l = (uint4*)wlds;
#pragma unroll
        for (int it = 0; it < 7; ++it) {
            const int e = tid + it * 512;
            if (e < 3456) l[e] = g[e];
        }
    }
    __syncthreads();   // the only barrier

    const int wave = tid >> 6;
    const int lane = tid & 63;
    const int n = lane & 15;
    const int q = lane >> 4;
    const int w0 = (wave & 3) * 16;
    const int rbase = (wave >> 2) * 4;
    const int hb = h0 + rbase;        // first output row of this wave

    f32x4 acc[4][4];
#pragma unroll
    for (int a = 0; a < 4; ++a)
#pragma unroll
        for (int j = 0; j < 4; ++j) acc[a][j] = (f32x4)0.f;

    const char* xTb = (const char*)xT;
    const int lane_off = q * 1056 + (w0 + n) * 16;

    auto WF = [&](int f) -> bf16x8 {
        return *(const bf16x8*)(wlds + f * 512 + q * 128 + (n & 7) * 16);
    };
    const bf16x8 zf = {0, 0, 0, 0, 0, 0, 0, 0};

#pragma unroll
    for (int du = 0; du < 3; ++du) {
        const int up = u + du - 1;
        if (up < 0 || up >= 5) continue;              // wave-uniform; zero contribution
#pragma unroll
        for (int dv = 0; dv < 3; ++dv) {
            const int vp = v + dv - 1;
            if (vp < 0 || vp >= 5) continue;          // wave-uniform; zero contribution

            const char* base = xTb + (size_t)((b * 25 + up * 5 + vp) * 64) * XROW + lane_off;

#pragma unroll
            for (int dw = 0; dw < 3; ++dw) {
                // 6 x-rows (4 outputs + h-halo) for this dw column
                bf16x8 F[6];
#pragma unroll
                for (int r = 0; r < 6; ++r) {
                    const int hr = hb + r - 1;
                    F[r] = (hr < 0 || hr >= 64) ? zf
                         : *(const bf16x8*)(base + (size_t)hr * XROW + dw * 16);
                }

                // br0: uvx (conv u,v,h): taps (du,dv,t); only dw==1 contributes
                if (dw == 1) {
#pragma unroll
                    for (int t = 0; t < 3; ++t) {
                        const bf16x8 Wf = WF(du * 9 + dv * 3 + t);
#pragma unroll
                        for (int hh = 0; hh < 4; ++hh)
                            acc[0][hh] = mfma16(Wf, F[t + hh], acc[0][hh]);
                    }
                }
                // br1: uvy (conv u,v,w): taps (du,dv,dw); x-row = output row
                {
                    const bf16x8 Wf = WF(27 + du * 9 + dv * 3 + dw);
#pragma unroll
                    for (int hh = 0; hh < 4; ++hh)
                        acc[1][hh] = mfma16(Wf, F[hh + 1], acc[1][hh]);
                }
                // br2: uxy (conv u,h,w): taps (du,dh,dw); dv neutral (==1)
                if (dv == 1) {
#pragma unroll
                    for (int dh = 0; dh < 3; ++dh) {
                        const bf16x8 Wf = WF(54 + du * 9 + dh * 3 + dw);
#pragma unroll
                        for (int hh = 0; hh < 4; ++hh)
                            acc[2][hh] = mfma16(Wf, F[dh + hh], acc[2][hh]);
                    }
                }
                // br3: vxy (conv v,h,w): taps (dv,dh,dw); du neutral (==1)
                if (du == 1) {
#pragma unroll
                    for (int dh = 0; dh < 3; ++dh) {
                        const bf16x8 Wf = WF(81 + dv * 9 + dh * 3 + dw);
#pragma unroll
                        for (int hh = 0; hh < 4; ++hh)
                            acc[3][hh] = mfma16(Wf, F[dh + hh], acc[3][hh]);
                    }
                }
            }
        }
    }

    // ---------------- epilogue: bias + PReLU + store ----------------
    const float alph[4] = { aa0[0], aa1[0], aa2[0], aa3[0] };
    float* op = out + (size_t)b * SB_ + (size_t)u * SU_ + (size_t)v * SV_ + w0 + n;
    const bool act = (q < 2);
#pragma unroll
    for (int br = 0; br < 4; ++br) {
        const float* bp = (br == 0) ? bb0 : (br == 1) ? bb1 : (br == 2) ? bb2 : bb3;
        const f32x4 bv = *(const f32x4*)(bp + (q & 1) * 4);
#pragma unroll
        for (int hh = 0; hh < 4; ++hh) {
            const int h = hb + hh;
#pragma unroll
            for (int r = 0; r < 4; ++r) {
                float val = acc[br][hh][r] + bv[r];
                val = (val >= 0.f) ? val : alph[br] * val;
                if (act)
                    op[(size_t)(br * 8 + q * 4 + r) * SC_ + (size_t)h * 64] = val;
            }
        }
    }
}

extern "C" void kernel_launch(void* const* d_in, const int* in_sizes, int n_in,
                              void* d_out, int out_size, void* d_ws, size_t ws_size,
                              hipStream_t stream) {
    const float* x  = (const float*)d_in[0];
    const float* w0 = (const float*)d_in[1];
    const float* b0 = (const float*)d_in[2];
    const float* a0 = (const float*)d_in[3];
    const float* w1 = (const float*)d_in[4];
    const float* b1 = (const float*)d_in[5];
    const float* a1 = (const float*)d_in[6];
    const float* w2 = (const float*)d_in[7];
    const float* b2 = (const float*)d_in[8];
    const float* a2 = (const float*)d_in[9];
    const float* w3 = (const float*)d_in[10];
    const float* b3 = (const float*)d_in[11];
    const float* a3 = (const float*)d_in[12];
    float* out = (float*)d_out;

    unsigned short* xT = (unsigned short*)d_ws;
    unsigned short* bt = (unsigned short*)((char*)d_ws + BT_OFF);

    k_prep<<<3200 + 108, 256, 0, stream>>>(x, xT, w0, w1, w2, w3, bt);   // transpose + weights
    k_main<<<1600, 512, 0, stream>>>(                                    // 8b x 25buv x 8hs
        xT, bt, b0, a0, b1, a1, b2, a2, b3, a3, out);
}

// Round 2
// 275.245 us; speedup vs baseline: 1.0795x; 1.0343x over previous
//
#include <hip/hip_runtime.h>

// ---------------- problem constants ----------------
#define B_  8
#define C_  32
#define U_  5
#define V_  5
#define H_  64
#define W_  64

// x / out strides (fp32 elements): [B][32][U][V][H][W]
#define SV_ 4096
#define SU_ 20480
#define SC_ 102400
#define SB_ 3276800

// xT (bf16, padded): [row = ((b*25+u*5+v)*64+h)][cq(4)][wslot(66)][c8(8)]
//   wslot = w+1 ; slots 0 and 65 are zeros (SAME padding in w for free)
//   row stride = 4*66*16 = 4224 B ; total 12800*4224 = 54067200 B
//
// Weight table (paired A-frags, rows0-7 = branch lo, rows8-15 = branch hi):
//   FULL  region [0, 18432):      18 frags x 1024 B, layout [q(4)][row(16)][j(8)]
//     f 0..8  : T01 center (a=1,b=1): rows0-7 = br0(du,dv,t=1), rows8-15 = br1(du,dv,dw=1)
//     f 9..17 : T23 center (du=1,dv=1): rows0-7 = br2(1,a,b), rows8-15 = br3(1,a,b)
//   LO    region [18432, 37440):  36 frags x 528 B = 512 data [q][oc8][j8] + 16 B zeros
//     g 0..17 : T01 br0 singles (du,dv)x{t=0,t=2}   (read rows0-7; rows8-15 -> zero pad)
//     g 18..35: T23 br2 singles (dv==1, du in {0,2}) x (a,b)
//   HI    region [37440, 56448):  36 frags x 528 B  (read rows8-15; rows0-7 -> zero pad)
//     g 0..17 : T01 br1 singles (du,dv)x{dw=0,dw=2}
//     g 18..35: T23 br3 singles (du==1, dv in {0,2}) x (a,b)
#define XROW 4224
#define BT_OFF 54067200ull
#define BT_BYTES 56448

typedef short bf16x8 __attribute__((ext_vector_type(8)));
typedef float f32x4 __attribute__((ext_vector_type(4)));

__device__ __forceinline__ unsigned short f2bf(float f) {
    unsigned int u = __builtin_bit_cast(unsigned int, f);
    u = (u + 0x7FFFu + ((u >> 16) & 1u)) >> 16;   // RNE
    return (unsigned short)u;
}

__device__ __forceinline__ f32x4 mfma16(bf16x8 a, bf16x8 b, f32x4 c) {
    return __builtin_amdgcn_mfma_f32_16x16x32_bf16(a, b, c, 0, 0, 0);
}

// ---------------- K1: prep = transpose (blocks 0..3199) + weight table (3200..3289) ----
__global__ __launch_bounds__(256)
void k_prep(const float* __restrict__ x, unsigned short* __restrict__ xT,
            const float* __restrict__ w0, const float* __restrict__ w1,
            const float* __restrict__ w2, const float* __restrict__ w3,
            unsigned short* __restrict__ btab)
{
    if (blockIdx.x >= 3200) {
        const int f = blockIdx.x - 3200;   // 0..89
        const int tid = threadIdx.x;
        if (f < 18) {
            // FULL frag: 512 entries [q][row16][j8], byte base f*1024
            for (int e = tid; e < 512; e += 256) {
                const int q = e >> 7, row = (e >> 3) & 15, j = e & 7;
                const int c = q * 8 + j;
                float val;
                if (f < 9) {          // T01 center: du=f/3, dv=f%3, tap *,*,1
                    const int tap = (f / 3) * 9 + (f % 3) * 3 + 1;
                    val = (row < 8) ? w0[row * 864 + c * 27 + tap]
                                    : w1[(row - 8) * 864 + c * 27 + tap];
                } else {              // T23 center: du=dv=1, tap 1,a,b
                    const int tap = 9 + (f - 9);
                    val = (row < 8) ? w2[row * 864 + c * 27 + tap]
                                    : w3[(row - 8) * 864 + c * 27 + tap];
                }
                btab[f * 512 + e] = f2bf(val);
            }
        } else {
            const bool hi = (f >= 54);
            const int g = hi ? (f - 54) : (f - 18);        // 0..35
            const size_t base = (hi ? 37440u : 18432u) / 2 + (size_t)g * 264;
            for (int e = tid; e < 264; e += 256) {
                unsigned short outv = 0;                    // zero pad entries 256..263
                if (e < 256) {
                    const int q = e >> 6, oc = (e >> 3) & 7, j = e & 7;
                    const int c = q * 8 + j;
                    float val;
                    if (g < 18) {     // T01 singles: pair p=(du,dv), tap offset which*2
                        const int p = g >> 1, which = g & 1;
                        const int tap = (p / 3) * 9 + (p % 3) * 3 + which * 2;
                        val = hi ? w1[oc * 864 + c * 27 + tap]      // br1, dw=0/2
                                 : w0[oc * 864 + c * 27 + tap];     // br0, t =0/2
                    } else {          // T23 singles: outer = 0 or 2, tap outer,a,b
                        const int h2 = g - 18;
                        const int tap = (h2 / 9) * 18 + (h2 % 9);   // outer*9 + a*3+b
                        val = hi ? w3[oc * 864 + c * 27 + tap]      // br3 (du==1)
                                 : w2[oc * 864 + c * 27 + tap];     // br2 (dv==1)
                    }
                    outv = f2bf(val);
                }
                btab[base + e] = outv;
            }
        }
        return;
    }

    // ---- x fp32 [B,C,U,V,H,W] -> padded bf16 xT ----
    __shared__ float tl[C_ * 4 * 64];   // [c][h(4)][w(64)] fp32, 32 KB
    const int tid = threadIdx.x;
    int blk = blockIdx.x;
    const int hq = blk & 15; blk >>= 4;
    const int v = blk % 5; blk /= 5;
    const int u = blk % 5;
    const int b = blk / 5;
    const int h0 = hq * 4;

    const float* src = x + (size_t)b * SB_ + (size_t)u * SU_ + (size_t)v * SV_ + h0 * 64;
#pragma unroll
    for (int i = 0; i < 8; ++i) {
        const int e = tid + i * 256;
        const int c = e >> 6;
        const int rem = e & 63;
        const int h = rem >> 4;
        const int w4 = (rem & 15) * 4;
        const float4 val = *(const float4*)(src + (size_t)c * SC_ + h * 64 + w4);
        *(float4*)(tl + c * 256 + h * 64 + w4) = val;
    }
    __syncthreads();

    const int h = tid >> 6;
    const int w = tid & 63;
    unsigned short* dst = xT + (size_t)((b * 25 + u * 5 + v) * 64 + h0 + h) * (XROW / 2);
    const uint4 z = make_uint4(0u, 0u, 0u, 0u);
#pragma unroll
    for (int cq = 0; cq < 4; ++cq) {
        unsigned short s[8];
#pragma unroll
        for (int j = 0; j < 8; ++j)
            s[j] = f2bf(tl[(cq * 8 + j) * 256 + h * 64 + w]);
        uint4 o;
        o.x = (unsigned)s[0] | ((unsigned)s[1] << 16);
        o.y = (unsigned)s[2] | ((unsigned)s[3] << 16);
        o.z = (unsigned)s[4] | ((unsigned)s[5] << 16);
        o.w = (unsigned)s[6] | ((unsigned)s[7] << 16);
        *(uint4*)(dst + cq * 528 + (w + 1) * 8) = o;           // wslot = w+1
        if (w == 0)  *(uint4*)(dst + cq * 528 + 0)       = z;  // wslot 0
        if (w == 63) *(uint4*)(dst + cq * 528 + 65 * 8)  = z;  // wslot 65
    }
}

// ---------------- K2: main MFMA kernel (branch-paired A, scalar row addressing) ----
// grid 1600 = 8 b * 25 buv * 8 hs ; block 512 thr = 8 waves
// XCD-chunked: XCD (blk&7) owns batch b=(blk&7); hs fastest keeps (u,v) 9-neighborhood
// in that XCD's L2. wave: w-tile (wave&3)*16, h-quad rbase=(wave>>2)*4.
// A rows0-7 / 8-15 carry two branches -> acc01 (br0|br1), acc23 (br2|br3).
__global__ __launch_bounds__(512, 2)
void k_main(const unsigned short* __restrict__ xT,
            const unsigned short* __restrict__ btabu,
            const float* __restrict__ bb0, const float* __restrict__ aa0,
            const float* __restrict__ bb1, const float* __restrict__ aa1,
            const float* __restrict__ bb2, const float* __restrict__ aa2,
            const float* __restrict__ bb3, const float* __restrict__ aa3,
            float* __restrict__ out)
{
    __shared__ alignas(16) char wlds[BT_BYTES];

    const int tid = threadIdx.x;
    const int blk = blockIdx.x;
    const int b   = blk & 7;          // == XCD id
    const int i   = blk >> 3;         // 0..199
    const int buv = i >> 3;           // 0..24
    const int hs  = i & 7;
    const int v = buv % 5;
    const int u = buv / 5;
    const int h0 = hs * 8;

    // stage weight table to LDS (one time): 56448/16 = 3528 uint4
    {
        const uint4* g = (const uint4*)btabu;
        uint4* l = (uint4*)wlds;
#pragma unroll
        for (int it = 0; it < 7; ++it) {
            const int e = tid + it * 512;
            if (e < 3528) l[e] = g[e];
        }
    }
    __syncthreads();   // the only barrier

    const int wave = tid >> 6;
    const int lane = tid & 63;
    const int n = lane & 15;
    const int q = lane >> 4;
    const int w0 = (wave & 3) * 16;
    const int hb = h0 + (wave >> 2) * 4;
    const int hbu = __builtin_amdgcn_readfirstlane(hb);   // wave-uniform -> SGPR

    f32x4 acc01[4], acc23[4];
#pragma unroll
    for (int j = 0; j < 4; ++j) { acc01[j] = (f32x4)0.f; acc23[j] = (f32x4)0.f; }

    const char* xTb = (const char*)xT;
    const int lane_off = q * 1056 + (w0 + n) * 16;

    // per-lane A-frag offsets (computed once)
    const int off_full = q * 256 + n * 16;                           // [q][row16][j]
    const int off_lo   = (n < 8) ? (q * 128 + n * 16) : 512;         // data | zero pad
    const int off_hi   = (n < 8) ? 512 : (q * 128 + (n & 7) * 16);   // zero pad | data

    auto RF = [&](int f) -> bf16x8 {
        return *(const bf16x8*)(wlds + f * 1024 + off_full);
    };
    auto RL = [&](int g) -> bf16x8 {
        return *(const bf16x8*)(wlds + 18432 + g * 528 + off_lo);
    };
    auto RH = [&](int g) -> bf16x8 {
        return *(const bf16x8*)(wlds + 37440 + g * 528 + off_hi);
    };
    const bf16x8 zf = {0, 0, 0, 0, 0, 0, 0, 0};

#pragma unroll
    for (int du = 0; du < 3; ++du) {
        const int up = u + du - 1;
        if (up < 0 || up >= 5) continue;              // wave-uniform; zero contribution
#pragma unroll
        for (int dv = 0; dv < 3; ++dv) {
            const int vp = v + dv - 1;
            if (vp < 0 || vp >= 5) continue;          // wave-uniform; zero contribution

            const char* rb = xTb + (size_t)((b * 25 + up * 5 + vp) * 64) * XROW;
            const int p01 = du * 3 + dv;
            const bool t23 = (du == 1) || (dv == 1);  // compile-time per unrolled iter

#pragma unroll
            for (int bb = 0; bb < 3; ++bb) {
                const int rlo = (t23 || bb == 1) ? 0 : 1;
                const int rhi = (t23 || bb == 1) ? 5 : 4;
                bf16x8 F[6];
#pragma unroll
                for (int r = 0; r < 6; ++r) {
                    if (r < rlo || r > rhi) continue;               // compile-time
                    const int hr = hbu + r - 1;                     // scalar
                    F[r] = (hr < 0 || hr >= 64) ? zf
                         : *(const bf16x8*)(rb + (size_t)hr * XROW + lane_off + bb * 16);
                }

                // ---- T01 (acc01: rows0-7 br0, rows8-15 br1) ----
                if (bb == 1) {
                    const bf16x8 Wl0 = RL(p01 * 2 + 0);   // br0 t=0
                    const bf16x8 Wc  = RF(p01);           // br0 t=1 | br1 dw=1
                    const bf16x8 Wl2 = RL(p01 * 2 + 1);   // br0 t=2
#pragma unroll
                    for (int hh = 0; hh < 4; ++hh) {
                        acc01[hh] = mfma16(Wl0, F[0 + hh], acc01[hh]);
                        acc01[hh] = mfma16(Wc,  F[1 + hh], acc01[hh]);
                        acc01[hh] = mfma16(Wl2, F[2 + hh], acc01[hh]);
                    }
                } else {
                    const bf16x8 Wh = RH(p01 * 2 + (bb == 2 ? 1 : 0));  // br1 dw=0/2
#pragma unroll
                    for (int hh = 0; hh < 4; ++hh)
                        acc01[hh] = mfma16(Wh, F[1 + hh], acc01[hh]);
                }

                // ---- T23 (acc23: rows0-7 br2, rows8-15 br3) ----
                if (du == 1 && dv == 1) {
#pragma unroll
                    for (int a = 0; a < 3; ++a) {
                        const bf16x8 Wf = RF(9 + a * 3 + bb);
#pragma unroll
                        for (int hh = 0; hh < 4; ++hh)
                            acc23[hh] = mfma16(Wf, F[a + hh], acc23[hh]);
                    }
                } else if (dv == 1) {                 // br2 only (du = 0 or 2)
#pragma unroll
                    for (int a = 0; a < 3; ++a) {
                        const bf16x8 Wl = RL(18 + (du == 2 ? 9 : 0) + a * 3 + bb);
#pragma unroll
                        for (int hh = 0; hh < 4; ++hh)
                            acc23[hh] = mfma16(Wl, F[a + hh], acc23[hh]);
                    }
                } else if (du == 1) {                 // br3 only (dv = 0 or 2)
#pragma unroll
                    for (int a = 0; a < 3; ++a) {
                        const bf16x8 Wh = RH(18 + (dv == 2 ? 9 : 0) + a * 3 + bb);
#pragma unroll
                        for (int hh = 0; hh < 4; ++hh)
                            acc23[hh] = mfma16(Wh, F[a + hh], acc23[hh]);
                    }
                }
            }
        }
    }

    // ---------------- epilogue: bias + PReLU + store (all lanes useful) ----------------
    const int qh = q >> 1;     // 0: low branch of pair, 1: high branch
    const int ql = q & 1;
    const float* bp0 = qh ? bb1 : bb0;
    const float* bp1 = qh ? bb3 : bb2;
    const float al0 = qh ? aa1[0] : aa0[0];
    const float al1 = qh ? aa3[0] : aa2[0];
    const f32x4 bv0 = *(const f32x4*)(bp0 + ql * 4);
    const f32x4 bv1 = *(const f32x4*)(bp1 + ql * 4);

    float* op = out + (size_t)b * SB_ + (size_t)u * SU_ + (size_t)v * SV_ + w0 + n;
#pragma unroll
    for (int hh = 0; hh < 4; ++hh) {
        const int h = hbu + hh;
#pragma unroll
        for (int r = 0; r < 4; ++r) {
            // pair 0 -> channels 0..15 (br0|br1)
            float v0 = acc01[hh][r] + bv0[r];
            v0 = (v0 >= 0.f) ? v0 : al0 * v0;
            op[(size_t)(q * 4 + r) * SC_ + (size_t)h * 64] = v0;
            // pair 1 -> channels 16..31 (br2|br3)
            float v1 = acc23[hh][r] + bv1[r];
            v1 = (v1 >= 0.f) ? v1 : al1 * v1;
            op[(size_t)(16 + q * 4 + r) * SC_ + (size_t)h * 64] = v1;
        }
    }
}

extern "C" void kernel_launch(void* const* d_in, const int* in_sizes, int n_in,
                              void* d_out, int out_size, void* d_ws, size_t ws_size,
                              hipStream_t stream) {
    const float* x  = (const float*)d_in[0];
    const float* w0 = (const float*)d_in[1];
    const float* b0 = (const float*)d_in[2];
    const float* a0 = (const float*)d_in[3];
    const float* w1 = (const float*)d_in[4];
    const float* b1 = (const float*)d_in[5];
    const float* a1 = (const float*)d_in[6];
    const float* w2 = (const float*)d_in[7];
    const float* b2 = (const float*)d_in[8];
    const float* a2 = (const float*)d_in[9];
    const float* w3 = (const float*)d_in[10];
    const float* b3 = (const float*)d_in[11];
    const float* a3 = (const float*)d_in[12];
    float* out = (float*)d_out;

    unsigned short* xT = (unsigned short*)d_ws;
    unsigned short* bt = (unsigned short*)((char*)d_ws + BT_OFF);

    k_prep<<<3200 + 90, 256, 0, stream>>>(x, xT, w0, w1, w2, w3, bt);  // transpose + table
    k_main<<<1600, 512, 0, stream>>>(                                  // 8b x 25buv x 8hs
        xT, bt, b0, a0, b1, a1, b2, a2, b3, a3, out);
}